// Round 9
// baseline (37424.496 us; speedup 1.0000x reference)
//
#include <hip/hip_runtime.h>
#include <math.h>

typedef unsigned int u32;

#define T_SEQ   2048
#define NWG     256

// ---------------- workspace layout (bytes) ----------------
#define OFF_HBUF   0            // float[2][32][512] = 131072
#define OFF_CNT    131072       // u32[8][64] (8 counters, 256B apart) = 2048
#define OFF_XCC    133120       // u32[256] = 1024
#define OFF_CHK    134144       // u32 check-in counter (256B reserved)
#define OFF_LASTH  134400       // float[32][512] = 65536
#define WS_NEED    199936ull

// ---------------- fallback (round-2 proven) layout ----------------
#define FB_OFF_HBUF   0
#define FB_OFF_ARRIVE 131072
#define FB_OFF_LASTH  131328

__device__ __forceinline__ float sigm(float x) { return 1.0f / (1.0f + expf(-x)); }

// ---- h-data accessors ----
// SAFE: sc0 sc1 = bypass L1 + XCD-L2, LLC-coherent chip-wide (r8-proven).
// FAST: sc0 only = bypass L1, served by the XCD's own L2 (requires all
//       consumers on the same XCD — verified at runtime via XCC_ID).
__device__ __forceinline__ float4 ldg4s(const float* p) {
  float4 v;
  asm volatile("global_load_dwordx4 %0, %1, off sc0 sc1" : "=v"(v) : "v"(p) : "memory");
  return v;
}
__device__ __forceinline__ void stg1fs(float* p, float v) {
  asm volatile("global_store_dword %0, %1, off sc0 sc1" :: "v"(p), "v"(v) : "memory");
}
__device__ __forceinline__ float4 ldg4l(const float* p) {
  float4 v;
  asm volatile("global_load_dwordx4 %0, %1, off sc0" : "=v"(v) : "v"(p) : "memory");
  return v;
}
__device__ __forceinline__ void stg1fl(float* p, float v) {
  asm volatile("global_store_dword %0, %1, off sc0" :: "v"(p), "v"(v) : "memory");
}

// =====================================================================
// Sequential LSTM v4 body (structure = r8, twice-passed; only the h
// access flavor is templated).
// bg = bid&7 (4 batches), slot = bid>>3 (16 units -> 64 gate rows).
// Thread (kg = tid>>4, rg = tid&15): 4 gate rows, k-slice [kg*32,+32).
// W in VGPRs; operands deduped through swizzled LDS; shfl k-reduction;
// per-bg monotone arrive counter (agent atomics, r6-r8-proven).
// =====================================================================
template<bool FAST>
__device__ void lstm_body(const int* __restrict__ x, const int* __restrict__ attn,
                          const float* __restrict__ emb,
                          const float* __restrict__ Wih, const float* __restrict__ Whh,
                          const float* __restrict__ bih, const float* __restrict__ bhh,
                          float* __restrict__ hbuf, u32* __restrict__ counters,
                          float* __restrict__ lasth,
                          float4* El, float4* Hl, float* wred, float* gsc, int* s_dead_p)
{
  const int tid = threadIdx.x, bid = blockIdx.x;
  const int bg = bid & 7, slot = bid >> 3;
  const int kg = tid >> 4, rg = tid & 15;
  const int wv = tid >> 6, lane = tid & 63;

  u32* cnt = counters + bg * 64;   // 256B-padded per-bg counter

  // ---- W -> registers (64 float4 = 256 VGPR) ----
  float4 wE[4][8], wH[4][8];
#pragma unroll
  for (int i = 0; i < 4; ++i) {
    int rr = rg * 4 + i, g = rr >> 4, uu = rr & 15;
    const float* pE = Wih + (size_t)(g * 512 + slot * 16 + uu) * 512 + kg * 32;
    const float* pH = Whh + (size_t)(g * 512 + slot * 16 + uu) * 512 + kg * 32;
#pragma unroll
    for (int q = 0; q < 8; ++q) {
      wE[i][q] = *(const float4*)(pE + 4 * q);
      wH[i][q] = *(const float4*)(pH + 4 * q);
    }
  }

  // ---- staging geometry (2 unique chunks of 512 per thread) ----
  const int c0_ = tid, c1_ = tid + 256;
  const int j0 = c0_ >> 7, w0 = c0_ & 127;
  const int j1 = c1_ >> 7, w1 = c1_ & 127;
  const int p0 = j0 * 128 + (w0 >> 3) * 8 + (((w0 & 7) + (w0 >> 3)) & 7);
  const int p1 = j1 * 128 + (w1 >> 3) * 8 + (((w1 & 7) + (w1 >> 3)) & 7);

  // ---- lengths (partials in gsc) ----
  {
    int b = tid & 3, c = tid >> 2;
    const int4* ap = (const int4*)(attn + (size_t)(bg * 4 + b) * 2048 + c * 32);
    int s = 0;
#pragma unroll
    for (int k = 0; k < 8; ++k) { int4 a = ap[k]; s += a.x + a.y + a.z + a.w; }
    gsc[c * 4 + b] = (float)s;
  }
  __syncthreads();
  int len = 0; float c_reg = 0.f;
  float bI = 0, bF = 0, bG = 0, bO = 0;
  if (tid < 64) {
    int b = tid & 3, uu = tid >> 2;
    int s = 0;
#pragma unroll
    for (int c = 0; c < 64; ++c) s += (int)gsc[c * 4 + b];
    len = s - 1; if (len < 0) len = T_SEQ - 1;
    int gu = slot * 16 + uu;
    bI = bih[gu]        + bhh[gu];
    bF = bih[512 + gu]  + bhh[512 + gu];
    bG = bih[1024 + gu] + bhh[1024 + gu];
    bO = bih[1536 + gu] + bhh[1536 + gu];
  }
  __syncthreads();   // gsc reusable

  bool dead = false;

  for (int t = 0; t < T_SEQ; ++t) {
    // ---- emb stage: 2 unique coalesced chunks/thread -> swizzled LDS ----
    {
      int xr0 = x[(size_t)(bg * 4 + j0) * 2048 + t];
      int xr1 = x[(size_t)(bg * 4 + j1) * 2048 + t];
      float4 e0 = *(const float4*)(emb + (size_t)xr0 * 512 + w0 * 4);
      float4 e1 = *(const float4*)(emb + (size_t)xr1 * 512 + w1 * 4);
      El[p0] = e0;
      El[p1] = e1;
    }
    __syncthreads();

    float acc[4][4];
#pragma unroll
    for (int i = 0; i < 4; ++i) { acc[i][0] = 0.f; acc[i][1] = 0.f; acc[i][2] = 0.f; acc[i][3] = 0.f; }

    // ---- emb FMA from LDS (h-independent; overlaps producer tail) ----
#pragma unroll
    for (int j = 0; j < 4; ++j)
#pragma unroll
      for (int q = 0; q < 8; ++q) {
        float4 ev = El[j * 128 + kg * 8 + ((q + kg) & 7)];
#pragma unroll
        for (int i = 0; i < 4; ++i) {
          acc[i][j] += wE[i][q].x * ev.x; acc[i][j] += wE[i][q].y * ev.y;
          acc[i][j] += wE[i][q].z * ev.z; acc[i][j] += wE[i][q].w * ev.w;
        }
      }

    // ---- barrier: lane 0 polls the bg counter ----
    if (tid == 0 && !dead) {
      int it = 0;
      const u32 target = (u32)(t << 5);        // 32*t
      while (__hip_atomic_load(cnt, __ATOMIC_RELAXED, __HIP_MEMORY_SCOPE_AGENT) < target) {
        if (++it > (1 << 16)) { *s_dead_p = 1; break; }   // watchdog: no hang
        __builtin_amdgcn_s_sleep(4);
      }
    }
    __syncthreads();
    if (*s_dead_p) dead = true;

    // ---- h stage: 2 unique coalesced chunks/thread -> LDS ----
    {
      const float* hsrc = hbuf + (((t + 1) & 1) << 14) + (size_t)(bg * 4) * 512;
      float4 h0, h1;
      if (FAST) { h0 = ldg4l(hsrc + (size_t)j0 * 512 + w0 * 4);
                  h1 = ldg4l(hsrc + (size_t)j1 * 512 + w1 * 4); }
      else      { h0 = ldg4s(hsrc + (size_t)j0 * 512 + w0 * 4);
                  h1 = ldg4s(hsrc + (size_t)j1 * 512 + w1 * 4); }
      asm volatile("s_waitcnt vmcnt(0)" ::: "memory");
      __builtin_amdgcn_sched_barrier(0);
      Hl[p0] = h0;
      Hl[p1] = h1;
    }
    __syncthreads();

    // ---- h FMA from LDS ----
#pragma unroll
    for (int j = 0; j < 4; ++j)
#pragma unroll
      for (int q = 0; q < 8; ++q) {
        float4 hv = Hl[j * 128 + kg * 8 + ((q + kg) & 7)];
#pragma unroll
        for (int i = 0; i < 4; ++i) {
          acc[i][j] += wH[i][q].x * hv.x; acc[i][j] += wH[i][q].y * hv.y;
          acc[i][j] += wH[i][q].z * hv.z; acc[i][j] += wH[i][q].w * hv.w;
        }
      }

    // ---- k-reduction: shfl over kg within wave, LDS over 4 waves ----
#pragma unroll
    for (int i = 0; i < 4; ++i)
#pragma unroll
      for (int j = 0; j < 4; ++j) {
        float v = acc[i][j];
        v += __shfl_xor(v, 16, 64);   // kg ^ 1
        v += __shfl_xor(v, 32, 64);   // kg ^ 2
        acc[i][j] = v;
      }
    if ((lane >> 4) == 0) {
#pragma unroll
      for (int i = 0; i < 4; ++i)
#pragma unroll
        for (int j = 0; j < 4; ++j)
          wred[wv * 272 + rg * 17 + i * 4 + j] = acc[i][j];
    }
    __syncthreads();
    {
      int rr = tid >> 2, j = tid & 3;
      int base = (rr >> 2) * 17 + (rr & 3) * 4 + j;
      gsc[tid] = ((wred[base] + wred[272 + base]) +
                  (wred[544 + base] + wred[816 + base]));
    }
    __syncthreads();

    // ---- activations + h post (wave 0), then counter post ----
    if (tid < 64) {
      int b = tid & 3, uu = tid >> 2;
      float gi = gsc[0 * 64 + uu * 4 + b] + bI;
      float gf = gsc[1 * 64 + uu * 4 + b] + bF;
      float gg = gsc[2 * 64 + uu * 4 + b] + bG;
      float go = gsc[3 * 64 + uu * 4 + b] + bO;
      float iv = sigm(gi), fv = sigm(gf), ov = sigm(go), gv = tanhf(gg);
      c_reg = fv * c_reg + iv * gv;
      float hval = ov * tanhf(c_reg);
      int bglob = bg * 4 + b, unit = slot * 16 + uu;
      float* hd = hbuf + ((t & 1) << 14) + (bglob << 9) + unit;
      if (FAST) stg1fl(hd, hval); else stg1fs(hd, hval);
      if (t == len) lasth[(bglob << 9) + unit] = hval;
    }
    asm volatile("s_waitcnt vmcnt(0)" ::: "memory");   // h stores at coherency point
    if (tid == 0)
      __hip_atomic_fetch_add(cnt, 1u, __ATOMIC_RELAXED, __HIP_MEMORY_SCOPE_AGENT);
  }
}

__global__ void __launch_bounds__(256, 1)
lstm_seq(const int* __restrict__ x, const int* __restrict__ attn,
         const float* __restrict__ emb,
         const float* __restrict__ Wih, const float* __restrict__ Whh,
         const float* __restrict__ bih, const float* __restrict__ bhh,
         float* __restrict__ hbuf, u32* __restrict__ counters,
         u32* __restrict__ xccs, u32* __restrict__ chk,
         float* __restrict__ lasth)
{
  __shared__ __align__(16) float4 El[512];
  __shared__ __align__(16) float4 Hl[512];
  __shared__ __align__(16) float wred[4 * 272];
  __shared__ float gsc[256];
  __shared__ int s_dead;
  __shared__ int s_fast;

  const int tid = threadIdx.x, bid = blockIdx.x;
  const int bg = bid & 7;

  // ---- one-time handshake: publish XCC_ID, global check-in, per-bg verdict ----
  // (r2-proven primitives only: agent fetch_add + agent atomic_load poll.)
  if (tid == 0) {
    s_dead = 0;
    u32 xcc = __builtin_amdgcn_s_getreg(63508) & 0xfu;   // HW_REG_XCC_ID, 32-bit
    __hip_atomic_store(xccs + bid, xcc, __ATOMIC_RELAXED, __HIP_MEMORY_SCOPE_AGENT);
    __hip_atomic_fetch_add(chk, 1u, __ATOMIC_RELEASE, __HIP_MEMORY_SCOPE_AGENT);
    int it = 0, ok = 1;
    while (__hip_atomic_load(chk, __ATOMIC_ACQUIRE, __HIP_MEMORY_SCOPE_AGENT) < NWG) {
      if (++it > (1 << 18)) { ok = 0; break; }           // timeout -> safe path
      __builtin_amdgcn_s_sleep(8);
    }
    if (ok) {
      u32 ref = __hip_atomic_load(xccs + bg, __ATOMIC_RELAXED, __HIP_MEMORY_SCOPE_AGENT);
      for (int s2 = 1; s2 < 32; ++s2) {
        u32 v = __hip_atomic_load(xccs + bg + 8 * s2, __ATOMIC_RELAXED, __HIP_MEMORY_SCOPE_AGENT);
        ok &= (v == ref);
      }
    }
    s_fast = ok;
  }
  __syncthreads();

  if (s_fast)
    lstm_body<true>(x, attn, emb, Wih, Whh, bih, bhh, hbuf, counters, lasth,
                    El, Hl, wred, gsc, &s_dead);
  else
    lstm_body<false>(x, attn, emb, Wih, Whh, bih, bhh, hbuf, counters, lasth,
                     El, Hl, wred, gsc, &s_dead);
}

// =====================================================================
// FC head
// =====================================================================
__global__ void __launch_bounds__(128)
fc_kernel(const float* __restrict__ lasth, const float* __restrict__ fcW,
          const float* __restrict__ fcb, float* __restrict__ out)
{
  int tid = threadIdx.x;
  int b = tid >> 2, n = tid & 3;
  const float4* h4 = (const float4*)(lasth + (size_t)b * 512);
  const float4* w4 = (const float4*)(fcW + (size_t)n * 512);
  float s0 = 0.f, s1 = 0.f, s2 = 0.f, s3 = 0.f;
#pragma unroll 8
  for (int k = 0; k < 128; ++k) {
    float4 a = h4[k], c = w4[k];
    s0 += a.x * c.x; s1 += a.y * c.y; s2 += a.z * c.z; s3 += a.w * c.w;
  }
  out[b * 4 + n] = fcb[n] + ((s0 + s1) + (s2 + s3));
}

// =====================================================================
// Fallback: round-2 proven persistent kernel (only if ws too small)
// =====================================================================
__device__ __forceinline__ void gl2lds16(const void* gsrc, void* ldst) {
  __builtin_amdgcn_global_load_lds(
      (const __attribute__((address_space(1))) u32*)gsrc,
      (__attribute__((address_space(3))) u32*)ldst, 16, 0, 0);
}

__global__ void __launch_bounds__(256)
lstm_persist(const int* __restrict__ xidx, const int* __restrict__ attn,
             const float* __restrict__ emb,
             const float* __restrict__ Wih, const float* __restrict__ Whh,
             const float* __restrict__ bih, const float* __restrict__ bhh,
             float* __restrict__ hbuf, float* __restrict__ lasth,
             u32* __restrict__ arrive)
{
  __shared__ __align__(16) float Wl[8][1024];
  __shared__ __align__(16) float ul[2][32][64];
  __shared__ float gsc[32][8];

  const int tid  = threadIdx.x;
  const int wg   = blockIdx.x;
  const int lane = tid & 63;
  const int wv   = tid >> 6;
  const int r    = tid & 7;
  const int bb   = tid >> 3;
  const int brl  = bb & 7;

#pragma unroll 2
  for (int i = 0; i < 8; ++i) {
    int ci = i * 256 + tid;
    int rr = ci >> 8;
    int cc = ci & 255;
    int R  = ((rr >> 1) << 9) + (wg * 2 + (rr & 1));
    const float* src = (cc < 128) ? (Wih + (size_t)R * 512 + cc * 4)
                                  : (Whh + (size_t)R * 512 + (cc - 128) * 4);
    float4 v = *(const float4*)src;
    int slot = cc ^ (rr & 7);
    *(float4*)&Wl[rr][slot * 4] = v;
  }
  float bias;
  {
    int R = ((r >> 1) << 9) + (wg * 2 + (r & 1));
    bias = bih[R] + bhh[R];
  }
  {
    int pb = tid >> 3, pc = tid & 7;
    const int4* ap = (const int4*)(attn + pb * 2048 + pc * 256);
    int s = 0;
#pragma unroll 8
    for (int k = 0; k < 64; ++k) { int4 a = ap[k]; s += a.x + a.y + a.z + a.w; }
    gsc[pb][pc] = (float)s;
  }
  __syncthreads();
  int   len_reg = 0;
  float c_reg   = 0.f;
  if (tid < 64) {
    int b2 = tid & 31;
    int s = 0;
#pragma unroll
    for (int k = 0; k < 8; ++k) s += (int)gsc[b2][k];
    len_reg = s - 1;
    if (len_reg < 0) len_reg = 2047;
  }
  __syncthreads();

  const int idx_b = 8 * wv + (lane & 7);
  int idx_cur = xidx[(size_t)idx_b * 2048];

  for (int t = 0; t < T_SEQ; ++t) {
    int idx_next = (t < T_SEQ - 1) ? xidx[(size_t)idx_b * 2048 + t + 1] : 0;
    float a0 = bias, a1 = 0.f, a2 = 0.f, a3 = 0.f;
    const float* hsrc = hbuf + (((t + 1) & 1) << 14);

    auto stageE = [&](int jt, int buf) {
#pragma unroll
      for (int q = 0; q < 2; ++q) {
        int rlq = 4 * q + (lane >> 4);
        int sc = lane & 15;
        int kc = sc ^ (rlq & 7);
        int rowg = __shfl(idx_cur, rlq, 64);
        const float* g = emb + (size_t)rowg * 512 + jt * 64 + kc * 4;
        gl2lds16(g, (void*)&ul[buf][8 * wv + 4 * q][0]);
      }
    };
    auto stageH = [&](int jt, int buf) {
#pragma unroll
      for (int q = 0; q < 2; ++q) {
        int rlq = 4 * q + (lane >> 4);
        int sc = lane & 15;
        int kc = sc ^ (rlq & 7);
        int blq = 8 * wv + rlq;
        const float* g = hsrc + (size_t)blq * 512 + jt * 64 + kc * 4;
        gl2lds16(g, (void*)&ul[buf][8 * wv + 4 * q][0]);
      }
    };
    auto computeT = [&](int jg, int buf) {
#pragma unroll
      for (int kc = 0; kc < 16; ++kc) {
        float4 uv4 = *(const float4*)&ul[buf][bb][(kc ^ brl) * 4];
        float4 wv4 = *(const float4*)&Wl[r][(((jg << 4) + kc) ^ r) * 4];
        a0 += uv4.x * wv4.x; a1 += uv4.y * wv4.y;
        a2 += uv4.z * wv4.z; a3 += uv4.w * wv4.w;
      }
    };

    stageE(0, 0);
#pragma unroll
    for (int jt = 0; jt < 8; ++jt) {
      if (jt < 7) { stageE(jt + 1, (jt + 1) & 1); asm volatile("s_waitcnt vmcnt(2)" ::: "memory"); }
      else       { asm volatile("s_waitcnt vmcnt(0)" ::: "memory"); }
      computeT(jt, jt & 1);
    }

    if (tid == 0) {
      u32 target = (u32)t << 8;
      while (__hip_atomic_load(arrive, __ATOMIC_RELAXED, __HIP_MEMORY_SCOPE_AGENT) < target)
        __builtin_amdgcn_s_sleep(2);
    }
    __syncthreads();
    __builtin_amdgcn_fence(__ATOMIC_ACQUIRE, "agent");

    stageH(0, 0);
#pragma unroll
    for (int jt = 0; jt < 8; ++jt) {
      if (jt < 7) { stageH(jt + 1, (jt + 1) & 1); asm volatile("s_waitcnt vmcnt(2)" ::: "memory"); }
      else       { asm volatile("s_waitcnt vmcnt(0)" ::: "memory"); }
      computeT(8 + jt, jt & 1);
    }

    gsc[bb][r] = a0 + a1 + a2 + a3;
    __syncthreads();
    if (tid < 64) {
      int u  = tid >> 5;
      int b2 = tid & 31;
      float gi = gsc[b2][u];
      float gf = gsc[b2][2 + u];
      float gg = gsc[b2][4 + u];
      float go = gsc[b2][6 + u];
      float iv = sigm(gi), fv = sigm(gf), ov = sigm(go);
      float gv = tanhf(gg);
      c_reg = fv * c_reg + iv * gv;
      float hv = ov * tanhf(c_reg);
      int unit = (wg << 1) + u;
      hbuf[((t & 1) << 14) + (b2 << 9) + unit] = hv;
      if (t == len_reg) lasth[(b2 << 9) + unit] = hv;
      __builtin_amdgcn_fence(__ATOMIC_RELEASE, "agent");
      if (tid == 0)
        __hip_atomic_fetch_add(arrive, 1u, __ATOMIC_RELAXED, __HIP_MEMORY_SCOPE_AGENT);
    }
    idx_cur = idx_next;
  }
}

extern "C" void kernel_launch(void* const* d_in, const int* in_sizes, int n_in,
                              void* d_out, int out_size, void* d_ws, size_t ws_size,
                              hipStream_t stream) {
  const int*   x    = (const int*)d_in[0];
  const int*   attn = (const int*)d_in[1];
  const float* emb  = (const float*)d_in[2];
  const float* Wih  = (const float*)d_in[3];
  const float* Whh  = (const float*)d_in[4];
  const float* bih  = (const float*)d_in[5];
  const float* bhh  = (const float*)d_in[6];
  const float* fcW  = (const float*)d_in[7];
  const float* fcb  = (const float*)d_in[8];
  float* out = (float*)d_out;
  char* ws = (char*)d_ws;

  if (ws_size >= WS_NEED) {
    float* hbuf  = (float*)(ws + OFF_HBUF);
    u32*   cnts  = (u32*)(ws + OFF_CNT);
    u32*   xccs  = (u32*)(ws + OFF_XCC);
    u32*   chk   = (u32*)(ws + OFF_CHK);
    float* lasth = (float*)(ws + OFF_LASTH);

    (void)hipMemsetAsync(ws, 0, OFF_LASTH, stream);   // hbuf+cnts+xccs+chk

    hipLaunchKernelGGL(lstm_seq, dim3(NWG), dim3(256), 0, stream,
                       x, attn, emb, Wih, Whh, bih, bhh, hbuf, cnts, xccs, chk, lasth);
    hipLaunchKernelGGL(fc_kernel, dim3(1), dim3(128), 0, stream,
                       lasth, fcW, fcb, out);
  } else {
    float* hbuf   = (float*)(ws + FB_OFF_HBUF);
    u32*   arrive = (u32*)(ws + FB_OFF_ARRIVE);
    float* lasth  = (float*)(ws + FB_OFF_LASTH);
    (void)hipMemsetAsync(ws, 0, 131072 + 256, stream);
    hipLaunchKernelGGL(lstm_persist, dim3(256), dim3(256), 0, stream,
                       x, attn, emb, Wih, Whh, bih, bhh, hbuf, lasth, arrive);
    hipLaunchKernelGGL(fc_kernel, dim3(1), dim3(128), 0, stream,
                       lasth, fcW, fcb, out);
  }
}

// Round 10
// 13601.344 us; speedup vs baseline: 2.7515x; 2.7515x over previous
//
#include <hip/hip_runtime.h>
#include <math.h>

typedef unsigned int u32;

#define T_SEQ   2048
#define NWG     256

// ---------------- workspace layout (bytes) ----------------
#define OFF_HBUF   0            // float[2][32][512] = 131072
#define OFF_CNT    131072       // u32[4][64] (4 counters, 256B apart) = 1024 (2048 reserved)
#define OFF_LASTH  133120       // float[32][512] = 65536
#define WS_NEED    198656ull

// ---------------- fallback (round-2 proven) layout ----------------
#define FB_OFF_HBUF   0
#define FB_OFF_ARRIVE 131072
#define FB_OFF_LASTH  131328

#define DYN_LDS_BYTES 148480    // Wl 131072 + Hl 16384 + gsc 1024

__device__ __forceinline__ float sigm(float x) { return 1.0f / (1.0f + expf(-x)); }

// ---- LLC-coherent accessors (sc0 sc1 = bypass L1 + XCD L2); r8-proven ----
__device__ __forceinline__ float4 ldg4s(const float* p) {
  float4 v;
  asm volatile("global_load_dwordx4 %0, %1, off sc0 sc1" : "=v"(v) : "v"(p) : "memory");
  return v;
}
__device__ __forceinline__ void stg1fs(float* p, float v) {
  asm volatile("global_store_dword %0, %1, off sc0 sc1" :: "v"(p), "v"(v) : "memory");
}

// =====================================================================
// Sequential LSTM v5: 256 WGs x 256 threads, 1 WG/CU (148 KB dynamic LDS).
// ug = bid>>2 owns 8 units -> 32 gate rows (row r = gate*8 + uu).
// bg = bid&3 owns 8 batches.
// W slice (32 x 1024) lives in LDS, XOR-swizzled (NOT in VGPRs — r6-r9's
// wE/wH[4][8] arrays = 512 floats/thread exceeded the 256-VGPR file and
// spilled to scratch: the invariant ~100 GB FETCH across r6-r9).
// Thread (wv = tid>>6, lane): kg = lane>>2 (k-slice of 32 floats/phase),
// inner = lane&3 -> rowg = wv*2+(inner>>1) (4 rows), batchg = inner&1 (4 b).
// Per phase: w[4][8] float4 from LDS (reused over 4 batches), operands:
//   emb = plain cached global loads (L1/L2 absorb; 16 KB/WG/step unique),
//   h   = sc0sc1 -> swizzled LDS (dedup, r8-proven).
// k-reduction: 4x shfl_xor (kg = lane bits 2..5); waves own disjoint rows.
// Sync: per-bg monotone counter (agent atomics, r6-r8-proven), target 64*t;
// h posted sc0sc1 + vmcnt(0) drain before post. Watchdog -> no hang.
// =====================================================================
__global__ void __launch_bounds__(256, 1)
lstm_seq(const int* __restrict__ x, const int* __restrict__ attn,
         const float* __restrict__ emb,
         const float* __restrict__ Wih, const float* __restrict__ Whh,
         const float* __restrict__ bih, const float* __restrict__ bhh,
         float* __restrict__ hbuf, u32* __restrict__ counters,
         float* __restrict__ lasth)
{
  extern __shared__ __align__(16) char smem[];
  float4* Wl4 = (float4*)smem;                       // [32 rows][256 chunks] swizzled
  float4* Hl4 = (float4*)(smem + 131072);            // [8 b][128 chunks] swizzled
  float*  gsc = (float*)(smem + 131072 + 16384);     // [32][8]
  __shared__ int s_dead;

  const int tid = threadIdx.x, bid = blockIdx.x;
  const int ug = bid >> 2, bg = bid & 3;
  const int wv = tid >> 6, lane = tid & 63;
  const int kg = lane >> 2, inner = lane & 3;
  const int rowg = wv * 2 + (inner >> 1);            // 0..7 -> rows rowg*4..+4
  const int bbase = (inner & 1) * 4;                 // local batches bbase..+4

  u32* cnt = counters + bg * 64;                     // 256B-padded per-bg counter

  // ---- W slice -> LDS, swizzled (one-time) ----
  // raw chunk c (0..255) of row r: stored at (c&~7) | ((c&7) + ((c>>3)&15) + (r>>2)) & 7
#pragma unroll
  for (int k = 0; k < 32; ++k) {
    int cf = tid + k * 256;            // 0..8191
    int r  = cf >> 8, c = cf & 255;
    int R  = (r >> 3) * 512 + ug * 8 + (r & 7);      // gate*512 + unit
    const float* src = (c < 128) ? (Wih + (size_t)R * 512 + c * 4)
                                 : (Whh + (size_t)R * 512 + (c - 128) * 4);
    float4 v = *(const float4*)src;
    int p = r * 256 + (c & ~7) + (((c & 7) + ((c >> 3) & 15) + (r >> 2)) & 7);
    Wl4[p] = v;
  }

  // ---- lengths (partials in gsc as [32 chunks][8 b]) ----
  {
    int b = tid & 7, c = tid >> 3;     // c in [0,32)
    const int4* ap = (const int4*)(attn + (size_t)(bg * 8 + b) * 2048 + c * 64);
    int s = 0;
#pragma unroll
    for (int k = 0; k < 16; ++k) { int4 a = ap[k]; s += a.x + a.y + a.z + a.w; }
    gsc[c * 8 + b] = (float)s;
  }
  if (tid == 0) s_dead = 0;
  __syncthreads();
  int len = 0; float c_reg = 0.f;
  float bI = 0, bF = 0, bG = 0, bO = 0;
  if (tid < 64) {
    int b = tid & 7, uu = tid >> 3;
    int s = 0;
#pragma unroll
    for (int c = 0; c < 32; ++c) s += (int)gsc[c * 8 + b];
    len = s - 1; if (len < 0) len = T_SEQ - 1;
    int gu = ug * 8 + uu;
    bI = bih[gu]        + bhh[gu];
    bF = bih[512 + gu]  + bhh[512 + gu];
    bG = bih[1024 + gu] + bhh[1024 + gu];
    bO = bih[1536 + gu] + bhh[1536 + gu];
  }
  __syncthreads();   // gsc reusable

  bool dead = false;
  float4 w[4][8];    // per-phase W fragment: 4 rows x 32 floats (128 VGPR)

  for (int t = 0; t < T_SEQ; ++t) {
    float acc[4][4];
#pragma unroll
    for (int i = 0; i < 4; ++i) { acc[i][0] = 0.f; acc[i][1] = 0.f; acc[i][2] = 0.f; acc[i][3] = 0.f; }

    // ---- emb phase (h-independent; overlaps producer tail) ----
#pragma unroll
    for (int i = 0; i < 4; ++i) {
      int r = rowg * 4 + i;
#pragma unroll
      for (int q = 0; q < 8; ++q)
        w[i][q] = Wl4[r * 256 + kg * 8 + ((q + kg + rowg) & 7)];   // phase 0 chunks
    }
#pragma unroll
    for (int jb = 0; jb < 4; ++jb) {
      int xr = x[(size_t)(bg * 8 + bbase + jb) * 2048 + t];
      const float4* ep = (const float4*)(emb + (size_t)xr * 512 + kg * 32);
      float4 e[8];
#pragma unroll
      for (int q = 0; q < 8; ++q) e[q] = ep[q];
#pragma unroll
      for (int q = 0; q < 8; ++q)
#pragma unroll
        for (int i = 0; i < 4; ++i) {
          acc[i][jb] += w[i][q].x * e[q].x; acc[i][jb] += w[i][q].y * e[q].y;
          acc[i][jb] += w[i][q].z * e[q].z; acc[i][jb] += w[i][q].w * e[q].w;
        }
    }

    // ---- barrier: lane 0 polls the bg counter (64 WGs/bg, target 64t) ----
    if (tid == 0 && !dead) {
      int it = 0;
      const u32 target = (u32)(t << 6);
      while (__hip_atomic_load(cnt, __ATOMIC_RELAXED, __HIP_MEMORY_SCOPE_AGENT) < target) {
        if (++it > (1 << 16)) { s_dead = 1; break; }   // watchdog: no hang
        __builtin_amdgcn_s_sleep(4);
      }
    }
    __syncthreads();
    if (s_dead) dead = true;

    // ---- h stage: 4 unique coalesced sc0sc1 float4/thread -> swizzled LDS ----
    {
      const float* hsrc = hbuf + (((t + 1) & 1) << 14) + (size_t)(bg * 8) * 512;
      float4 hv[4];
      int pp[4];
#pragma unroll
      for (int k = 0; k < 4; ++k) {
        int cf = tid + k * 256;        // 0..1023
        int b = cf >> 7, c = cf & 127;
        hv[k] = ldg4s(hsrc + (size_t)b * 512 + c * 4);
        pp[k] = b * 128 + (c & ~7) + (((c & 7) + (c >> 3) + b) & 7);
      }
      asm volatile("s_waitcnt vmcnt(0)" ::: "memory");
      __builtin_amdgcn_sched_barrier(0);
#pragma unroll
      for (int k = 0; k < 4; ++k) Hl4[pp[k]] = hv[k];
    }
    __syncthreads();

    // ---- h phase: W(phase 1) from LDS, u from Hl ----
#pragma unroll
    for (int i = 0; i < 4; ++i) {
      int r = rowg * 4 + i;
#pragma unroll
      for (int q = 0; q < 8; ++q)
        w[i][q] = Wl4[r * 256 + 128 + kg * 8 + ((q + kg + rowg) & 7)];   // phase 1
    }
#pragma unroll
    for (int jb = 0; jb < 4; ++jb) {
      int bl = bbase + jb;
      float4 e[8];
#pragma unroll
      for (int q = 0; q < 8; ++q)
        e[q] = Hl4[bl * 128 + kg * 8 + ((q + kg + bl) & 7)];
#pragma unroll
      for (int q = 0; q < 8; ++q)
#pragma unroll
        for (int i = 0; i < 4; ++i) {
          acc[i][jb] += w[i][q].x * e[q].x; acc[i][jb] += w[i][q].y * e[q].y;
          acc[i][jb] += w[i][q].z * e[q].z; acc[i][jb] += w[i][q].w * e[q].w;
        }
    }

    // ---- k-reduction: 4x shfl_xor over kg (lane bits 2..5); rows are
    //      wave-disjoint, so no cross-wave pass needed ----
#pragma unroll
    for (int i = 0; i < 4; ++i)
#pragma unroll
      for (int j = 0; j < 4; ++j) {
        float v = acc[i][j];
        v += __shfl_xor(v, 4, 64);
        v += __shfl_xor(v, 8, 64);
        v += __shfl_xor(v, 16, 64);
        v += __shfl_xor(v, 32, 64);
        acc[i][j] = v;
      }
    if (lane < 16) {                   // kgl = lane>>2 picks which row to publish
      int kgl = lane >> 2;
      int r = rowg * 4 + kgl;          // rowg from this lane's inner = lane&3
#pragma unroll
      for (int j = 0; j < 4; ++j)
        gsc[r * 8 + bbase + j] = acc[kgl][j];
    }
    __syncthreads();

    // ---- activations + sc0sc1 h post (wave 0), then counter post ----
    if (tid < 64) {
      int b = tid & 7, uu = tid >> 3;
      float gi = gsc[(0 * 8 + uu) * 8 + b] + bI;
      float gf = gsc[(1 * 8 + uu) * 8 + b] + bF;
      float gg = gsc[(2 * 8 + uu) * 8 + b] + bG;
      float go = gsc[(3 * 8 + uu) * 8 + b] + bO;
      float iv = sigm(gi), fv = sigm(gf), ov = sigm(go), gv = tanhf(gg);
      c_reg = fv * c_reg + iv * gv;
      float hval = ov * tanhf(c_reg);
      int bglob = bg * 8 + b, unit = ug * 8 + uu;
      float* hd = hbuf + ((t & 1) << 14) + (bglob << 9) + unit;
      stg1fs(hd, hval);
      if (t == len) lasth[(bglob << 9) + unit] = hval;
      asm volatile("s_waitcnt vmcnt(0)" ::: "memory");   // wave0 stores at LLC
      if (tid == 0)
        __hip_atomic_fetch_add(cnt, 1u, __ATOMIC_RELAXED, __HIP_MEMORY_SCOPE_AGENT);
    }
  }
}

// =====================================================================
// FC head
// =====================================================================
__global__ void __launch_bounds__(128)
fc_kernel(const float* __restrict__ lasth, const float* __restrict__ fcW,
          const float* __restrict__ fcb, float* __restrict__ out)
{
  int tid = threadIdx.x;
  int b = tid >> 2, n = tid & 3;
  const float4* h4 = (const float4*)(lasth + (size_t)b * 512);
  const float4* w4 = (const float4*)(fcW + (size_t)n * 512);
  float s0 = 0.f, s1 = 0.f, s2 = 0.f, s3 = 0.f;
#pragma unroll 8
  for (int k = 0; k < 128; ++k) {
    float4 a = h4[k], c = w4[k];
    s0 += a.x * c.x; s1 += a.y * c.y; s2 += a.z * c.z; s3 += a.w * c.w;
  }
  out[b * 4 + n] = fcb[n] + ((s0 + s1) + (s2 + s3));
}

// =====================================================================
// Fallback: round-2 proven persistent kernel (only if ws too small)
// =====================================================================
__device__ __forceinline__ void gl2lds16(const void* gsrc, void* ldst) {
  __builtin_amdgcn_global_load_lds(
      (const __attribute__((address_space(1))) u32*)gsrc,
      (__attribute__((address_space(3))) u32*)ldst, 16, 0, 0);
}

__global__ void __launch_bounds__(256)
lstm_persist(const int* __restrict__ xidx, const int* __restrict__ attn,
             const float* __restrict__ emb,
             const float* __restrict__ Wih, const float* __restrict__ Whh,
             const float* __restrict__ bih, const float* __restrict__ bhh,
             float* __restrict__ hbuf, float* __restrict__ lasth,
             u32* __restrict__ arrive)
{
  __shared__ __align__(16) float Wl[8][1024];
  __shared__ __align__(16) float ul[2][32][64];
  __shared__ float gsc[32][8];

  const int tid  = threadIdx.x;
  const int wg   = blockIdx.x;
  const int lane = tid & 63;
  const int wv   = tid >> 6;
  const int r    = tid & 7;
  const int bb   = tid >> 3;
  const int brl  = bb & 7;

#pragma unroll 2
  for (int i = 0; i < 8; ++i) {
    int ci = i * 256 + tid;
    int rr = ci >> 8;
    int cc = ci & 255;
    int R  = ((rr >> 1) << 9) + (wg * 2 + (rr & 1));
    const float* src = (cc < 128) ? (Wih + (size_t)R * 512 + cc * 4)
                                  : (Whh + (size_t)R * 512 + (cc - 128) * 4);
    float4 v = *(const float4*)src;
    int slot = cc ^ (rr & 7);
    *(float4*)&Wl[rr][slot * 4] = v;
  }
  float bias;
  {
    int R = ((r >> 1) << 9) + (wg * 2 + (r & 1));
    bias = bih[R] + bhh[R];
  }
  {
    int pb = tid >> 3, pc = tid & 7;
    const int4* ap = (const int4*)(attn + pb * 2048 + pc * 256);
    int s = 0;
#pragma unroll 8
    for (int k = 0; k < 64; ++k) { int4 a = ap[k]; s += a.x + a.y + a.z + a.w; }
    gsc[pb][pc] = (float)s;
  }
  __syncthreads();
  int   len_reg = 0;
  float c_reg   = 0.f;
  if (tid < 64) {
    int b2 = tid & 31;
    int s = 0;
#pragma unroll
    for (int k = 0; k < 8; ++k) s += (int)gsc[b2][k];
    len_reg = s - 1;
    if (len_reg < 0) len_reg = 2047;
  }
  __syncthreads();

  const int idx_b = 8 * wv + (lane & 7);
  int idx_cur = xidx[(size_t)idx_b * 2048];

  for (int t = 0; t < T_SEQ; ++t) {
    int idx_next = (t < T_SEQ - 1) ? xidx[(size_t)idx_b * 2048 + t + 1] : 0;
    float a0 = bias, a1 = 0.f, a2 = 0.f, a3 = 0.f;
    const float* hsrc = hbuf + (((t + 1) & 1) << 14);

    auto stageE = [&](int jt, int buf) {
#pragma unroll
      for (int q = 0; q < 2; ++q) {
        int rlq = 4 * q + (lane >> 4);
        int sc = lane & 15;
        int kc = sc ^ (rlq & 7);
        int rowg = __shfl(idx_cur, rlq, 64);
        const float* g = emb + (size_t)rowg * 512 + jt * 64 + kc * 4;
        gl2lds16(g, (void*)&ul[buf][8 * wv + 4 * q][0]);
      }
    };
    auto stageH = [&](int jt, int buf) {
#pragma unroll
      for (int q = 0; q < 2; ++q) {
        int rlq = 4 * q + (lane >> 4);
        int sc = lane & 15;
        int kc = sc ^ (rlq & 7);
        int blq = 8 * wv + rlq;
        const float* g = hsrc + (size_t)blq * 512 + jt * 64 + kc * 4;
        gl2lds16(g, (void*)&ul[buf][8 * wv + 4 * q][0]);
      }
    };
    auto computeT = [&](int jg, int buf) {
#pragma unroll
      for (int kc = 0; kc < 16; ++kc) {
        float4 uv4 = *(const float4*)&ul[buf][bb][(kc ^ brl) * 4];
        float4 wv4 = *(const float4*)&Wl[r][(((jg << 4) + kc) ^ r) * 4];
        a0 += uv4.x * wv4.x; a1 += uv4.y * wv4.y;
        a2 += uv4.z * wv4.z; a3 += uv4.w * wv4.w;
      }
    };

    stageE(0, 0);
#pragma unroll
    for (int jt = 0; jt < 8; ++jt) {
      if (jt < 7) { stageE(jt + 1, (jt + 1) & 1); asm volatile("s_waitcnt vmcnt(2)" ::: "memory"); }
      else       { asm volatile("s_waitcnt vmcnt(0)" ::: "memory"); }
      computeT(jt, jt & 1);
    }

    if (tid == 0) {
      u32 target = (u32)t << 8;
      while (__hip_atomic_load(arrive, __ATOMIC_RELAXED, __HIP_MEMORY_SCOPE_AGENT) < target)
        __builtin_amdgcn_s_sleep(2);
    }
    __syncthreads();
    __builtin_amdgcn_fence(__ATOMIC_ACQUIRE, "agent");

    stageH(0, 0);
#pragma unroll
    for (int jt = 0; jt < 8; ++jt) {
      if (jt < 7) { stageH(jt + 1, (jt + 1) & 1); asm volatile("s_waitcnt vmcnt(2)" ::: "memory"); }
      else       { asm volatile("s_waitcnt vmcnt(0)" ::: "memory"); }
      computeT(8 + jt, jt & 1);
    }

    gsc[bb][r] = a0 + a1 + a2 + a3;
    __syncthreads();
    if (tid < 64) {
      int u  = tid >> 5;
      int b2 = tid & 31;
      float gi = gsc[b2][u];
      float gf = gsc[b2][2 + u];
      float gg = gsc[b2][4 + u];
      float go = gsc[b2][6 + u];
      float iv = sigm(gi), fv = sigm(gf), ov = sigm(go);
      float gv = tanhf(gg);
      c_reg = fv * c_reg + iv * gv;
      float hv = ov * tanhf(c_reg);
      int unit = (wg << 1) + u;
      hbuf[((t & 1) << 14) + (b2 << 9) + unit] = hv;
      if (t == len_reg) lasth[(b2 << 9) + unit] = hv;
      __builtin_amdgcn_fence(__ATOMIC_RELEASE, "agent");
      if (tid == 0)
        __hip_atomic_fetch_add(arrive, 1u, __ATOMIC_RELAXED, __HIP_MEMORY_SCOPE_AGENT);
    }
    idx_cur = idx_next;
  }
}

extern "C" void kernel_launch(void* const* d_in, const int* in_sizes, int n_in,
                              void* d_out, int out_size, void* d_ws, size_t ws_size,
                              hipStream_t stream) {
  const int*   x    = (const int*)d_in[0];
  const int*   attn = (const int*)d_in[1];
  const float* emb  = (const float*)d_in[2];
  const float* Wih  = (const float*)d_in[3];
  const float* Whh  = (const float*)d_in[4];
  const float* bih  = (const float*)d_in[5];
  const float* bhh  = (const float*)d_in[6];
  const float* fcW  = (const float*)d_in[7];
  const float* fcb  = (const float*)d_in[8];
  float* out = (float*)d_out;
  char* ws = (char*)d_ws;

  if (ws_size >= WS_NEED) {
    float* hbuf  = (float*)(ws + OFF_HBUF);
    u32*   cnts  = (u32*)(ws + OFF_CNT);
    float* lasth = (float*)(ws + OFF_LASTH);

    (void)hipFuncSetAttribute((const void*)lstm_seq,
                              hipFuncAttributeMaxDynamicSharedMemorySize, DYN_LDS_BYTES);
    (void)hipMemsetAsync(ws, 0, 133120, stream);   // hbuf + counters

    hipLaunchKernelGGL(lstm_seq, dim3(NWG), dim3(256), DYN_LDS_BYTES, stream,
                       x, attn, emb, Wih, Whh, bih, bhh, hbuf, cnts, lasth);
    hipLaunchKernelGGL(fc_kernel, dim3(1), dim3(128), 0, stream,
                       lasth, fcW, fcb, out);
  } else {
    float* hbuf   = (float*)(ws + FB_OFF_HBUF);
    u32*   arrive = (u32*)(ws + FB_OFF_ARRIVE);
    float* lasth  = (float*)(ws + FB_OFF_LASTH);
    (void)hipMemsetAsync(ws, 0, 131072 + 256, stream);
    hipLaunchKernelGGL(lstm_persist, dim3(256), dim3(256), 0, stream,
                       x, attn, emb, Wih, Whh, bih, bhh, hbuf, lasth, arrive);
    hipLaunchKernelGGL(fc_kernel, dim3(1), dim3(128), 0, stream,
                       lasth, fcW, fcb, out);
  }
}